// Round 12
// baseline (129.679 us; speedup 1.0000x reference)
//
#include <hip/hip_runtime.h>

// Problem constants (from reference)
#define N_CELL 60000
#define N_GENE 4000
#define DIM    128
#define EPS_BN 1e-5f

#define NBUCKET 469            // ceil(60000/128) buckets of 128 cells
#define CAP     3700           // per-bucket capacity: mean 3200, +8.8 sigma
#define CAP_Q   1024           // per-quarter capacity: mean 800, +8 sigma
#define PBLK_I4 2048           // int4s per partition block (= 8192 edges)
#define NB_GEMM ((N_CELL + 63) / 64)     // 938 main-GEMM blocks

// Workspace layout (4-byte words).  Zeroed region = first WS_ZERO words.
//   stats  [512]             @ 0        (sum,sumsq,mu,istd — 128 each)
//   gcur   [512]             @ 512      (int; per-bucket edge counters)
//   --- end of zeroed region (1024 words) ---
//   msgb   [N_CELL*DIM bf16] @ 1024      (3.84M w) -> ends 3,841,024
//   preb   [N_CELL*DIM bf16] @ 3,841,024 (3.84M w) -> ends 7,681,024
//   ygene  [N_GENE*DIM bf16] @ 7,681,024 (256K w)  -> ends 7,937,024
//   gedges [NBUCKET*CAP u32] @ 8,193,024           -> ends 9,928,324
//   Wb     [16384 bf16]      @ 9,928,324 (8192 w)  -> ends 9,936,516
#define WS_STATS  0
#define WS_GCUR   512
#define WS_ZERO   1024
#define WS_MSGB   1024
#define WS_PREB   3841024
#define WS_YGENE  7681024
#define WS_GEDGE  8193024
#define WS_WB     9928324

typedef __bf16 bf16x8 __attribute__((ext_vector_type(8)));
typedef float  f32x4  __attribute__((ext_vector_type(4)));

__device__ __forceinline__ float bflo(unsigned int u) {
  return __uint_as_float(u << 16);
}
__device__ __forceinline__ float bfhi(unsigned int u) {
  return __uint_as_float(u & 0xFFFF0000u);
}
__device__ __forceinline__ float bf2f(unsigned short u) {
  return __uint_as_float((unsigned int)u << 16);
}
__device__ __forceinline__ unsigned short f2bf(float f) {
  const __bf16 b = (__bf16)f;
  return __builtin_bit_cast(unsigned short, b);
}

// ---------------------------------------------------------------------------
// Kernel 1: y_gene = bf16(x_gene @ Wl)  — fp32 accumulate, bf16 store.
// ---------------------------------------------------------------------------
__global__ __launch_bounds__(128) void ygene_gemm(
    const float* __restrict__ xg, const float* __restrict__ Wl,
    unsigned short* __restrict__ y) {
  const int j  = threadIdx.x;
  const int r0 = blockIdx.x * 8;
  float acc[8] = {};
  for (int k = 0; k < DIM; ++k) {
    const float w = Wl[k * DIM + j];
#pragma unroll
    for (int r = 0; r < 8; ++r)
      acc[r] += xg[(size_t)(r0 + r) * DIM + k] * w;
  }
#pragma unroll
  for (int r = 0; r < 8; ++r)
    y[(size_t)(r0 + r) * DIM + j] = f2bf(acc[r]);
}

// ---------------------------------------------------------------------------
// conv_w: Wr fp32 [128k][128j] -> fragment-ordered bf16 for 16x16x32 MFMA.
// ---------------------------------------------------------------------------
__global__ __launch_bounds__(256) void conv_w(
    const float* __restrict__ w, unsigned short* __restrict__ wb) {
  const int i = blockIdx.x * 256 + threadIdx.x;  // 0..16383
  const int k = i >> 7, j = i & 127;
  const int chunk = (k >> 5) * 8 + (j >> 4);
  const int lane  = ((k >> 3) & 3) * 16 + (j & 15);
  const int e     = k & 7;
  wb[(chunk * 64 + lane) * 8 + e] = f2bf(w[i]);
}

// ---------------------------------------------------------------------------
// partition_edges: pack (dst<<12 | src) and counting-sort 8192-edge chunks
// into 469 global bucket regions (bucket = dst>>7).  LDS-local sort makes
// the global writes contiguous runs instead of random 4 B scatters.
// hist/off/cur/gbase sized 512 and FULLY zeroed (scan reads 0..511).
// ---------------------------------------------------------------------------
__global__ __launch_bounds__(256) void partition_edges(
    const int* __restrict__ src, const int* __restrict__ dst,
    int* __restrict__ gcur, unsigned int* __restrict__ gedges, int E) {
  __shared__ unsigned int sorted[PBLK_I4 * 4];  // 32 KB
  __shared__ int hist[512], off[512];
  __shared__ int cur[512], gbase[512];
  __shared__ int sc[256];
  __shared__ int tot;
  const int t = threadIdx.x;

  hist[t] = 0;
  hist[256 + t] = 0;
  __syncthreads();

  // ---- load 32 edges/thread into registers, pack, histogram ----
  const int n4    = E >> 2;                 // E divisible by 4 (1.5e6)
  const int base4 = blockIdx.x * PBLK_I4;
  unsigned int pk[32];
#pragma unroll
  for (int k = 0; k < 8; ++k) {
    const int i4 = base4 + k * 256 + t;
    if (i4 < n4) {
      const int4 d4 = ((const int4*)dst)[i4];
      const int4 s4 = ((const int4*)src)[i4];
      pk[k * 4 + 0] = ((unsigned)d4.x << 12) | (unsigned)s4.x;
      pk[k * 4 + 1] = ((unsigned)d4.y << 12) | (unsigned)s4.y;
      pk[k * 4 + 2] = ((unsigned)d4.z << 12) | (unsigned)s4.z;
      pk[k * 4 + 3] = ((unsigned)d4.w << 12) | (unsigned)s4.w;
#pragma unroll
      for (int j = 0; j < 4; ++j)
        atomicAdd(&hist[pk[k * 4 + j] >> 19], 1);
    } else {
#pragma unroll
      for (int j = 0; j < 4; ++j) pk[k * 4 + j] = 0xFFFFFFFFu;
    }
  }
  __syncthreads();

  // ---- exclusive scan of hist[0..511]: pair-sum + Hillis-Steele(256) ----
  const int h0 = hist[2 * t];
  const int h1 = hist[2 * t + 1];
  const int pairsum = h0 + h1;
  sc[t] = pairsum;
  __syncthreads();
#pragma unroll
  for (int o = 1; o < 256; o <<= 1) {
    const int v = (t >= o) ? sc[t - o] : 0;
    __syncthreads();
    sc[t] += v;
    __syncthreads();
  }
  {
    const int excl = sc[t] - pairsum;       // exclusive over pairs
    off[2 * t]     = excl;
    off[2 * t + 1] = excl + h0;
    if (t == 255) tot = sc[255];
  }
  __syncthreads();

  // ---- reserve global ranges, zero local cursors ----
  cur[t] = 0;
  cur[256 + t] = 0;
  for (int i = t; i < 512; i += 256)
    gbase[i] = (i < NBUCKET && hist[i] > 0) ? atomicAdd(&gcur[i], hist[i]) : 0;
  __syncthreads();

  // ---- local scatter: registers -> bucket-sorted LDS ----
#pragma unroll
  for (int k = 0; k < 32; ++k) {
    const unsigned int p = pk[k];
    if (p != 0xFFFFFFFFu) {
      const int b   = p >> 19;
      const int pos = atomicAdd(&cur[b], 1);
      sorted[off[b] + pos] = p;
    }
  }
  __syncthreads();

  // ---- coalesced-run write-out ----
  for (int j = t; j < tot; j += 256) {
    const unsigned int p = sorted[j];
    const int b   = p >> 19;
    const int idx = gbase[b] + (j - off[b]);
    if (idx < CAP) gedges[(size_t)b * CAP + idx] = p;
  }
}

// ---------------------------------------------------------------------------
// bucket_aggregate: 4 blocks per bucket (32-cell quarters).  bf16 gather
// from L2-resident y_gene; msg written as bf16.
// ---------------------------------------------------------------------------
__global__ __launch_bounds__(256) void bucket_aggregate(
    const unsigned int* __restrict__ gedges, const int* __restrict__ gcur,
    const unsigned short* __restrict__ yb, unsigned short* __restrict__ msgb) {
  __shared__ unsigned short srt[CAP_Q];        // 2 KB: src per edge, cell-sorted
  __shared__ int counts[32], coff[32], ccur[32];
  __shared__ int sc[32];
  const int b = blockIdx.x >> 2;               // bucket
  const int q = blockIdx.x & 3;                // quarter (32 cells)
  const int t = threadIdx.x;

  int cnt = gcur[b];
  if (cnt > CAP) cnt = CAP;

  if (t < 32) { counts[t] = 0; ccur[t] = 0; }
  __syncthreads();

  // ---- stage bucket edges, keep only our quarter, histogram ----
  unsigned int e[15];                          // 15*256 = 3840 >= CAP
#pragma unroll
  for (int k = 0; k < 15; ++k) {
    const int j = k * 256 + t;
    unsigned int v = (j < cnt) ? gedges[(size_t)b * CAP + j] : 0xFFFFFFFFu;
    // cell = (v>>12)&127; quarter = cell>>5 = (v>>17)&3
    if (v != 0xFFFFFFFFu && (int)((v >> 17) & 3) == q) {
      e[k] = v;
      atomicAdd(&counts[(v >> 12) & 31], 1);
    } else {
      e[k] = 0xFFFFFFFFu;
    }
  }
  __syncthreads();

  // ---- exclusive scan of counts[32] ----
  if (t < 32) sc[t] = counts[t];
  __syncthreads();
#pragma unroll
  for (int o = 1; o < 32; o <<= 1) {
    int v = 0;
    if (t < 32 && t >= o) v = sc[t - o];
    __syncthreads();
    if (t < 32) sc[t] += v;
    __syncthreads();
  }
  if (t < 32) coff[t] = sc[t] - counts[t];
  __syncthreads();

  // ---- scatter src indices into cell-sorted LDS (u16) ----
#pragma unroll
  for (int k = 0; k < 15; ++k) {
    if (e[k] != 0xFFFFFFFFu) {
      const int c   = (e[k] >> 12) & 31;
      const int pos = atomicAdd(&ccur[c], 1);
      const int idx = coff[c] + pos;
      if (idx < CAP_Q) srt[idx] = (unsigned short)(e[k] & 0xFFF);
    }
  }
  __syncthreads();

  // ---- per-cell bf16 gather: wave w owns cells [w*8, w*8+8) ----
  const int w    = t >> 6;
  const int lane = t & 63;
  const int grp  = lane >> 4;                  // edge group 0..3
  const int lsub = lane & 15;                  // 8-dim slice: dims lsub*8..+8
  for (int ci = 0; ci < 8; ++ci) {
    const int c     = w * 8 + ci;                  // cell within quarter
    const int gcell = b * 128 + q * 32 + c;
    if (gcell >= N_CELL) break;                    // wave-uniform
    const int beg = coff[c], num = counts[c];

    float a0[8] = {}, a1[8] = {};
    int ei = grp;
    for (; ei + 4 < num; ei += 8) {                // 2-deep, 4 groups
      const int s0 = srt[beg + ei];
      const int s1 = srt[beg + ei + 4];
      const uint4 v0 = *(const uint4*)(yb + (size_t)s0 * DIM + lsub * 8);
      const uint4 v1 = *(const uint4*)(yb + (size_t)s1 * DIM + lsub * 8);
      a0[0] += bflo(v0.x); a0[1] += bfhi(v0.x);
      a0[2] += bflo(v0.y); a0[3] += bfhi(v0.y);
      a0[4] += bflo(v0.z); a0[5] += bfhi(v0.z);
      a0[6] += bflo(v0.w); a0[7] += bfhi(v0.w);
      a1[0] += bflo(v1.x); a1[1] += bfhi(v1.x);
      a1[2] += bflo(v1.y); a1[3] += bfhi(v1.y);
      a1[4] += bflo(v1.z); a1[5] += bfhi(v1.z);
      a1[6] += bflo(v1.w); a1[7] += bfhi(v1.w);
    }
    if (ei < num) {                                // tail edge for this group
      const int s = srt[beg + ei];
      const uint4 v = *(const uint4*)(yb + (size_t)s * DIM + lsub * 8);
      a0[0] += bflo(v.x); a0[1] += bfhi(v.x);
      a0[2] += bflo(v.y); a0[3] += bfhi(v.y);
      a0[4] += bflo(v.z); a0[5] += bfhi(v.z);
      a0[6] += bflo(v.w); a0[7] += bfhi(v.w);
    }
    // combine the 4 edge-groups (lanes xor 16, xor 32 share lsub)
    float r[8];
#pragma unroll
    for (int d = 0; d < 8; ++d) {
      float s = a0[d] + a1[d];
      s += __shfl_xor(s, 16);
      s += __shfl_xor(s, 32);
      r[d] = s;
    }
    if (grp == 0) {
      const float ic = 1.0f / fmaxf((float)num, 1.0f);
      const unsigned int o0 =
          ((unsigned int)f2bf(r[1] * ic) << 16) | f2bf(r[0] * ic);
      const unsigned int o1 =
          ((unsigned int)f2bf(r[3] * ic) << 16) | f2bf(r[2] * ic);
      const unsigned int o2 =
          ((unsigned int)f2bf(r[5] * ic) << 16) | f2bf(r[4] * ic);
      const unsigned int o3 =
          ((unsigned int)f2bf(r[7] * ic) << 16) | f2bf(r[6] * ic);
      *(uint4*)(msgb + (size_t)gcell * DIM + lsub * 8) =
          make_uint4(o0, o1, o2, o3);
    }
  }
}

// ---------------------------------------------------------------------------
// main GEMM, R12: LDS-transposed VECTORIZED epilogue.  R11's invariant-40us
// profile (dur unchanged under 2x traffic + 2x grid) fingered the scalar
// 2-byte scatter epilogue (64 ops/thread) + 240K same-line stats atomics.
// Now: acc -> LDS (stride 129) -> wave w reads col strip [w*32,w*32+32),
// lane = row -> uint4 msgb loads + uint4 preb stores (16 B/lane).  BN stats
// moved OUT to bn_stats_bf16.
// ---------------------------------------------------------------------------
__global__ __launch_bounds__(256) void main_gemm_mfma(
    const float* __restrict__ xc, const unsigned short* __restrict__ wb,
    const float* __restrict__ bl, const unsigned short* __restrict__ msgb,
    unsigned short* __restrict__ preb) {
  __shared__ float smem[64 * 129];             // 33 KB; u16 view for A-stage
  unsigned short* a_lds = (unsigned short*)smem;
  const int t    = threadIdx.x;
  const int row0 = blockIdx.x * 64;

  // ---- stage A: fp32 -> bf16, swizzled; thread t: row t>>2, K-quarter t&3
  {
    const int row  = t >> 2;
    const int h    = t & 3;
    const int grow = row0 + row;
    const bool ok  = grow < N_CELL;
    const float* xrow = xc + (size_t)grow * DIM;
#pragma unroll
    for (int i = 0; i < 2; ++i) {
      const int kk = h * 32 + i * 16;
      float4 f0, f1, f2, f3;
      if (ok) {
        f0 = *(const float4*)(xrow + kk);
        f1 = *(const float4*)(xrow + kk + 4);
        f2 = *(const float4*)(xrow + kk + 8);
        f3 = *(const float4*)(xrow + kk + 12);
      } else {
        f0 = f1 = f2 = f3 = make_float4(0.f, 0.f, 0.f, 0.f);
      }
      const float fv[16] = {f0.x, f0.y, f0.z, f0.w, f1.x, f1.y, f1.z, f1.w,
                            f2.x, f2.y, f2.z, f2.w, f3.x, f3.y, f3.z, f3.w};
      union { unsigned short u[16]; uint4 q[2]; } pk;
#pragma unroll
      for (int e = 0; e < 16; ++e) pk.u[e] = f2bf(fv[e]);
      const int s0 = ((kk >> 3) + 0) ^ (row & 15);
      const int s1 = ((kk >> 3) + 1) ^ (row & 15);
      *(uint4*)&a_lds[row * 128 + s0 * 8] = pk.q[0];
      *(uint4*)&a_lds[row * 128 + s1 * 8] = pk.q[1];
    }
  }
  __syncthreads();

  const int w   = t >> 6, l = t & 63;
  const int l15 = l & 15, lq = l >> 4;

  f32x4 acc[4][2];
#pragma unroll
  for (int g = 0; g < 4; ++g)
#pragma unroll
    for (int c = 0; c < 2; ++c) acc[g][c] = (f32x4){0.f, 0.f, 0.f, 0.f};

#pragma unroll
  for (int ks = 0; ks < 4; ++ks) {
    bf16x8 bfr[2];
#pragma unroll
    for (int c = 0; c < 2; ++c) {
      const int cf = w * 2 + c;                 // col fragment 0..7
      bfr[c] = *(const bf16x8*)(wb +
                (size_t)(((ks * 8 + cf) * 64 + l) * 8));
    }
    bf16x8 afr[4];
#pragma unroll
    for (int g = 0; g < 4; ++g) {
      const int row = g * 16 + l15;             // row & 15 == l15
      const int s   = (ks * 4 + lq) ^ l15;
      afr[g] = *(const bf16x8*)&a_lds[row * 128 + s * 8];
    }
#pragma unroll
    for (int g = 0; g < 4; ++g)
#pragma unroll
      for (int c = 0; c < 2; ++c)
        acc[g][c] = __builtin_amdgcn_mfma_f32_16x16x32_bf16(
            afr[g], bfr[c], acc[g][c], 0, 0, 0);
  }

  // ---- acc -> LDS (fp32, stride 129: <=4-way write, 2-way read) ----
  __syncthreads();                 // all MFMA LDS reads done before overwrite
#pragma unroll
  for (int g = 0; g < 4; ++g) {
#pragma unroll
    for (int c = 0; c < 2; ++c) {
      const int col = (w * 2 + c) * 16 + l15;
#pragma unroll
      for (int r = 0; r < 4; ++r) {
        const int row = g * 16 + lq * 4 + r;
        smem[row * 129 + col] = acc[g][c][r];
      }
    }
  }
  __syncthreads();

  // ---- vectorized epilogue: wave w -> cols [w*32,w*32+32), lane = row ----
  {
    const int grow = row0 + l;
    if (grow < N_CELL) {
      const float* arow = smem + l * 129 + w * 32;
      const unsigned short* mrow = msgb + (size_t)grow * DIM + w * 32;
      unsigned short* prow = preb + (size_t)grow * DIM + w * 32;
#pragma unroll
      for (int i = 0; i < 4; ++i) {             // 8 cols per iteration
        const uint4 mv = *(const uint4*)(mrow + i * 8);
        const float* bp = bl + w * 32 + i * 8;
        float v0 = arow[i * 8 + 0] + bflo(mv.x) + bp[0];
        float v1 = arow[i * 8 + 1] + bfhi(mv.x) + bp[1];
        float v2 = arow[i * 8 + 2] + bflo(mv.y) + bp[2];
        float v3 = arow[i * 8 + 3] + bfhi(mv.y) + bp[3];
        float v4 = arow[i * 8 + 4] + bflo(mv.z) + bp[4];
        float v5 = arow[i * 8 + 5] + bfhi(mv.z) + bp[5];
        float v6 = arow[i * 8 + 6] + bflo(mv.w) + bp[6];
        float v7 = arow[i * 8 + 7] + bfhi(mv.w) + bp[7];
        const unsigned int o0 = ((unsigned int)f2bf(v1) << 16) | f2bf(v0);
        const unsigned int o1 = ((unsigned int)f2bf(v3) << 16) | f2bf(v2);
        const unsigned int o2 = ((unsigned int)f2bf(v5) << 16) | f2bf(v4);
        const unsigned int o3 = ((unsigned int)f2bf(v7) << 16) | f2bf(v6);
        *(uint4*)(prow + i * 8) = make_uint4(o0, o1, o2, o3);
      }
    }
  }
}

// ---------------------------------------------------------------------------
// bn_stats_bf16: per-column sum/sumsq over preb (coalesced streaming read,
// L2/L3-hot), one atomic per column per block.  Replaces in-GEMM BN fusion.
// ---------------------------------------------------------------------------
__global__ __launch_bounds__(256) void bn_stats_bf16(
    const unsigned short* __restrict__ preb, float* __restrict__ stats) {
  __shared__ float s1[2][128], s2[2][128];
  const int t  = threadIdx.x;
  const int tc = t & 127;
  const int tr = t >> 7;
  float a = 0.f, b = 0.f;
  for (int r = blockIdx.x * 2 + tr; r < N_CELL; r += gridDim.x * 2) {
    const float v = bf2f(preb[(size_t)r * DIM + tc]);
    a += v;
    b += v * v;
  }
  s1[tr][tc] = a;
  s2[tr][tc] = b;
  __syncthreads();
  if (tr == 0) {
    unsafeAtomicAdd(&stats[tc],       s1[0][tc] + s1[1][tc]);
    unsafeAtomicAdd(&stats[128 + tc], s2[0][tc] + s2[1][tc]);
  }
}

// ---------------------------------------------------------------------------
// bn_finalize: mu / inv_std from accumulated sums (1 block, ~2 us)
// ---------------------------------------------------------------------------
__global__ __launch_bounds__(128) void bn_finalize(float* __restrict__ stats) {
  const int j = threadIdx.x;
  const float mu  = stats[j] / (float)N_CELL;
  const float var = stats[128 + j] / (float)N_CELL - mu * mu;
  stats[256 + j] = mu;
  stats[384 + j] = rsqrtf(var + EPS_BN);
}

// ---------------------------------------------------------------------------
// bn_apply: read bf16 pre (L3-hot), write fp32 out
// ---------------------------------------------------------------------------
__global__ __launch_bounds__(256) void bn_apply(
    const unsigned short* __restrict__ preb, float* __restrict__ out,
    const float* __restrict__ stats) {
  const size_t total = (size_t)N_CELL * DIM / 8;
  const size_t step  = (size_t)gridDim.x * blockDim.x;
  for (size_t i = (size_t)blockIdx.x * blockDim.x + threadIdx.x; i < total;
       i += step) {
    const uint4 v = ((const uint4*)preb)[i];
    const int col = (int)((i * 8) & (DIM - 1));
    const float* mu = stats + 256 + col;
    const float* is = stats + 384 + col;
    float4 o0, o1;
    o0.x = (bflo(v.x) - mu[0]) * is[0];
    o0.y = (bfhi(v.x) - mu[1]) * is[1];
    o0.z = (bflo(v.y) - mu[2]) * is[2];
    o0.w = (bfhi(v.y) - mu[3]) * is[3];
    o1.x = (bflo(v.z) - mu[4]) * is[4];
    o1.y = (bfhi(v.z) - mu[5]) * is[5];
    o1.z = (bflo(v.w) - mu[6]) * is[6];
    o1.w = (bfhi(v.w) - mu[7]) * is[7];
    *(float4*)(out + i * 8)     = o0;
    *(float4*)(out + i * 8 + 4) = o1;
  }
}

// ---------------------------------------------------------------------------
extern "C" void kernel_launch(void* const* d_in, const int* in_sizes, int n_in,
                              void* d_out, int out_size, void* d_ws,
                              size_t ws_size, hipStream_t stream) {
  const float* x_cell = (const float*)d_in[0];
  const float* x_gene = (const float*)d_in[1];
  const float* Wl_gc  = (const float*)d_in[2];
  const float* bl_gc  = (const float*)d_in[3];
  const float* Wr_gc  = (const float*)d_in[4];
  // d_in[5..7] (cg weights) are dead: the gene branch never feeds the output.
  const int* gc_src = (const int*)d_in[8];
  const int* gc_dst = (const int*)d_in[9];
  const int  E      = in_sizes[8];

  const float* Wl1 = Wl_gc + DIM * DIM;   // layer 1 (last)
  const float* bl1 = bl_gc + DIM;
  const float* Wr1 = Wr_gc + DIM * DIM;

  float* ws    = (float*)d_ws;
  float* stats = ws + WS_STATS;
  int*   gcur  = (int*)(ws + WS_GCUR);
  unsigned short* msgb   = (unsigned short*)(ws + WS_MSGB);
  unsigned short* preb   = (unsigned short*)(ws + WS_PREB);
  unsigned short* ygene  = (unsigned short*)(ws + WS_YGENE);
  unsigned int*   gedges = (unsigned int*)(ws + WS_GEDGE);
  unsigned short* Wb     = (unsigned short*)(ws + WS_WB);
  float* out   = (float*)d_out;

  // zero stats + bucket counters (4 KB)
  hipMemsetAsync(d_ws, 0, (size_t)WS_ZERO * sizeof(float), stream);

  conv_w<<<64, 256, 0, stream>>>(Wr1, Wb);
  ygene_gemm<<<N_GENE / 8, 128, 0, stream>>>(x_gene, Wl1, ygene);

  const int npart = (E / 4 + PBLK_I4 - 1) / PBLK_I4;   // 184 blocks
  partition_edges<<<npart, 256, 0, stream>>>(gc_src, gc_dst, gcur, gedges, E);
  bucket_aggregate<<<NBUCKET * 4, 256, 0, stream>>>(gedges, gcur, ygene, msgb);

  main_gemm_mfma<<<NB_GEMM, 256, 0, stream>>>(x_cell, Wb, bl1, msgb, preb);

  bn_stats_bf16<<<512, 256, 0, stream>>>(preb, stats);
  bn_finalize<<<1, 128, 0, stream>>>(stats);
  bn_apply<<<2048, 256, 0, stream>>>(preb, out, stats);
}

// Round 13
// 93.732 us; speedup vs baseline: 1.3835x; 1.3835x over previous
//
#include <hip/hip_runtime.h>

// Problem constants (from reference)
#define N_CELL 60000
#define N_GENE 4000
#define DIM    128
#define EPS_BN 1e-5f

#define NBUCKET 938            // ceil(60000/64) buckets of 64 cells (= GEMM tile)
#define CAP_H   2048           // per-bucket capacity: mean 1600, +11 sigma
#define PBLK_I4 2048           // int4s per partition block (= 8192 edges)
#define NPART   184            // partition blocks (184*8192 >= 1.5M edges)
#define NCONV   64             // conv_w blocks
#define NYG     250            // ygene blocks (16 rows each)

// Workspace layout (4-byte words).  Zeroed region = first WS_ZERO words.
//   stats  [512]             @ 0         (sum,sumsq,mu,istd — 128 each)
//   gcur   [1024]            @ 512       (int; per-bucket counters, 938 used)
//   --- end of zeroed region (1536; round to 2048) ---
//   preb   [N_CELL*DIM bf16] @ 2048      (3.84M w)  -> ends 3,842,048
//   ygene  [N_GENE*DIM bf16] @ 3,842,048 (256K w)   -> ends 4,098,048
//   gedges [NBUCKET*CAP_H]   @ 4,098,048 (1.92M w)  -> ends 6,019,072
//   Wb     [16384 bf16]      @ 6,019,072 (8192 w)   -> ends 6,027,264 (24.1 MB)
#define WS_STATS  0
#define WS_GCUR   512
#define WS_ZERO   2048
#define WS_PREB   2048
#define WS_YGENE  3842048
#define WS_GEDGE  4098048
#define WS_WB     6019072

typedef __bf16 bf16x8 __attribute__((ext_vector_type(8)));
typedef float  f32x4  __attribute__((ext_vector_type(4)));

__device__ __forceinline__ float bflo(unsigned int u) {
  return __uint_as_float(u << 16);
}
__device__ __forceinline__ float bfhi(unsigned int u) {
  return __uint_as_float(u & 0xFFFF0000u);
}
__device__ __forceinline__ float bf2f(unsigned short u) {
  return __uint_as_float((unsigned int)u << 16);
}
__device__ __forceinline__ unsigned short f2bf(float f) {
  const __bf16 b = (__bf16)f;
  return __builtin_bit_cast(unsigned short, b);
}

// ---------------------------------------------------------------------------
// prep_fused: three independent prep stages in ONE dispatch.
//   blocks [0,184)    : partition edges -> 938 bucket regions (64 cells each)
//   blocks [184,248)  : conv_w (Wr fp32 -> fragment-ordered bf16)
//   blocks [248,498)  : ygene = bf16(x_gene @ Wl), 16 rows per block
// ---------------------------------------------------------------------------
__global__ __launch_bounds__(256) void prep_fused(
    const int* __restrict__ src, const int* __restrict__ dst,
    int* __restrict__ gcur, unsigned int* __restrict__ gedges,
    const float* __restrict__ wr, unsigned short* __restrict__ wb,
    const float* __restrict__ xg, const float* __restrict__ wl,
    unsigned short* __restrict__ ygene, int E) {
  __shared__ unsigned int sorted[PBLK_I4 * 4];  // 32 KB
  __shared__ int hist[1024], off[1024];
  __shared__ int cur[1024], gbase[1024];
  __shared__ int sc[256];
  __shared__ int tot;
  const int t = threadIdx.x;

  if (blockIdx.x >= NPART + NCONV) {
    // ---------------- ygene: 16 rows, 256 threads ----------------
    const int bb = blockIdx.x - (NPART + NCONV);
    const int j  = t & 127;
    const int r0 = bb * 16 + (t >> 7) * 8;
    float acc[8] = {};
    for (int k = 0; k < DIM; ++k) {
      const float w = wl[k * DIM + j];
#pragma unroll
      for (int r = 0; r < 8; ++r)
        acc[r] += xg[(size_t)(r0 + r) * DIM + k] * w;
    }
#pragma unroll
    for (int r = 0; r < 8; ++r)
      ygene[(size_t)(r0 + r) * DIM + j] = f2bf(acc[r]);
    return;
  }
  if (blockIdx.x >= NPART) {
    // ---------------- conv_w ----------------
    const int i = (blockIdx.x - NPART) * 256 + t;   // 0..16383
    const int k = i >> 7, j = i & 127;
    const int chunk = (k >> 5) * 8 + (j >> 4);
    const int lane  = ((k >> 3) & 3) * 16 + (j & 15);
    const int e     = k & 7;
    wb[(chunk * 64 + lane) * 8 + e] = f2bf(wr[i]);
    return;
  }

  // ---------------- partition (938 buckets, bucket = dst>>6) ----------------
  hist[t] = 0; hist[256 + t] = 0; hist[512 + t] = 0; hist[768 + t] = 0;
  __syncthreads();

  const int n4    = E >> 2;                 // E divisible by 4 (1.5e6)
  const int base4 = blockIdx.x * PBLK_I4;
  unsigned int pk[32];
#pragma unroll
  for (int k = 0; k < 8; ++k) {
    const int i4 = base4 + k * 256 + t;
    if (i4 < n4) {
      const int4 d4 = ((const int4*)dst)[i4];
      const int4 s4 = ((const int4*)src)[i4];
      pk[k * 4 + 0] = ((unsigned)d4.x << 12) | (unsigned)s4.x;
      pk[k * 4 + 1] = ((unsigned)d4.y << 12) | (unsigned)s4.y;
      pk[k * 4 + 2] = ((unsigned)d4.z << 12) | (unsigned)s4.z;
      pk[k * 4 + 3] = ((unsigned)d4.w << 12) | (unsigned)s4.w;
#pragma unroll
      for (int j = 0; j < 4; ++j)
        atomicAdd(&hist[pk[k * 4 + j] >> 18], 1);   // bucket = dst>>6, <938
    } else {
#pragma unroll
      for (int j = 0; j < 4; ++j) pk[k * 4 + j] = 0xFFFFFFFFu;
    }
  }
  __syncthreads();

  // ---- exclusive scan of hist[0..1023]: quad-sum + Hillis-Steele(256) ----
  // hist sized 1024 exactly; max index read = 4*255+3 = 1023 (no OOB).
  const int h0 = hist[4 * t], h1 = hist[4 * t + 1];
  const int h2 = hist[4 * t + 2], h3 = hist[4 * t + 3];
  const int qs = h0 + h1 + h2 + h3;
  sc[t] = qs;
  __syncthreads();
#pragma unroll
  for (int o = 1; o < 256; o <<= 1) {
    const int v = (t >= o) ? sc[t - o] : 0;
    __syncthreads();
    sc[t] += v;
    __syncthreads();
  }
  {
    const int excl = sc[t] - qs;
    off[4 * t]     = excl;
    off[4 * t + 1] = excl + h0;
    off[4 * t + 2] = excl + h0 + h1;
    off[4 * t + 3] = excl + h0 + h1 + h2;
    if (t == 255) tot = sc[255];
  }
  __syncthreads();

  // ---- reserve global ranges, zero local cursors ----
  cur[t] = 0; cur[256 + t] = 0; cur[512 + t] = 0; cur[768 + t] = 0;
  for (int i = t; i < 1024; i += 256)
    gbase[i] = (i < NBUCKET && hist[i] > 0) ? atomicAdd(&gcur[i], hist[i]) : 0;
  __syncthreads();

  // ---- local scatter: registers -> bucket-sorted LDS ----
#pragma unroll
  for (int k = 0; k < 32; ++k) {
    const unsigned int p = pk[k];
    if (p != 0xFFFFFFFFu) {
      const int b   = p >> 18;
      const int pos = atomicAdd(&cur[b], 1);
      sorted[off[b] + pos] = p;
    }
  }
  __syncthreads();

  // ---- coalesced-run write-out ----
  for (int j = t; j < tot; j += 256) {
    const unsigned int p = sorted[j];
    const int b   = p >> 18;
    const int idx = gbase[b] + (j - off[b]);
    if (idx < CAP_H) gedges[(size_t)b * CAP_H + idx] = p;
  }
}

// ---------------------------------------------------------------------------
// gemm_fused: one block per 64-cell tile (= one partition bucket).
//   P1: stage bucket edges, LDS counting sort by cell (64 counters)
//   P2: bf16 gather-aggregate from L2-resident ygene -> msg_lds (bf16)
//   P3: stage A (x_cell fp32->bf16, XOR-swizzled) -> MFMA x@Wr
//   P4: val = acc + msg + bias, IN-PLACE into msg_lds (reader==writer),
//       BN sum/sumsq via shfl_xor + one atomic per thread
//   P5: uint4 copy msg_lds -> preb
// Replaces bucket_aggregate + main_gemm + bn_stats and the msgb buffer.
// ---------------------------------------------------------------------------
__global__ __launch_bounds__(256) void gemm_fused(
    const unsigned int* __restrict__ gedges, const int* __restrict__ gcur,
    const unsigned short* __restrict__ yb, const float* __restrict__ xc,
    const unsigned short* __restrict__ wb, const float* __restrict__ bl,
    unsigned short* __restrict__ preb, float* __restrict__ stats) {
  // region: [0,8192) u16 = A-stage (16 KB); [8192,10240) u16 = srt (4 KB).
  // srt is dead before A-stage begins (P2 reads it, P3 writes region[0..8192)).
  __shared__ unsigned short region[10240];
  __shared__ unsigned short msg_lds[64 * 136];   // stride 136 u16 = 272 B (16B-aligned, quad-spread)
  __shared__ int counts[64], coff[64], ccur[64], sc64[64];
  __shared__ float ps[4][32], ps2[4][32];
  unsigned short* a_lds = region;
  unsigned short* srt   = region + 8192;

  const int b    = blockIdx.x;
  const int t    = threadIdx.x;
  const int row0 = b * 64;

  int cnt = gcur[b];
  if (cnt > CAP_H) cnt = CAP_H;

  if (t < 64) { counts[t] = 0; ccur[t] = 0; }
  __syncthreads();

  // ---- P1a: stage edges into registers + per-cell histogram ----
  unsigned int e[8];                             // 8*256 = 2048 = CAP_H
#pragma unroll
  for (int k = 0; k < 8; ++k) {
    const int j = k * 256 + t;
    e[k] = (j < cnt) ? gedges[(size_t)b * CAP_H + j] : 0xFFFFFFFFu;
    if (e[k] != 0xFFFFFFFFu) atomicAdd(&counts[(e[k] >> 12) & 63], 1);
  }
  __syncthreads();

  // ---- P1b: exclusive scan of counts[64] ----
  if (t < 64) sc64[t] = counts[t];
  __syncthreads();
#pragma unroll
  for (int o = 1; o < 64; o <<= 1) {
    int v = 0;
    if (t < 64 && t >= o) v = sc64[t - o];
    __syncthreads();
    if (t < 64) sc64[t] += v;
    __syncthreads();
  }
  if (t < 64) coff[t] = sc64[t] - counts[t];
  __syncthreads();

  // ---- P1c: scatter src indices into cell-sorted srt (u16) ----
#pragma unroll
  for (int k = 0; k < 8; ++k) {
    if (e[k] != 0xFFFFFFFFu) {
      const int c   = (e[k] >> 12) & 63;
      const int pos = atomicAdd(&ccur[c], 1);
      srt[coff[c] + pos] = (unsigned short)(e[k] & 0xFFF);
    }
  }
  __syncthreads();

  // ---- P2: bf16 gather; wave w owns cells [w*16, w*16+16) ----
  const int w    = t >> 6;
  const int l    = t & 63;
  const int grp  = l >> 4;                       // edge group 0..3
  const int lsub = l & 15;                       // 8-dim slice
  for (int ci = 0; ci < 16; ++ci) {
    const int c     = w * 16 + ci;
    const int gcell = row0 + c;
    if (gcell >= N_CELL) break;                  // wave-uniform (cells ascend)
    const int beg = coff[c], num = counts[c];

    float a0[8] = {}, a1[8] = {};
    int ei = grp;
    for (; ei + 4 < num; ei += 8) {              // 2-deep, 4 groups
      const int s0 = srt[beg + ei];
      const int s1 = srt[beg + ei + 4];
      const uint4 v0 = *(const uint4*)(yb + (size_t)s0 * DIM + lsub * 8);
      const uint4 v1 = *(const uint4*)(yb + (size_t)s1 * DIM + lsub * 8);
      a0[0] += bflo(v0.x); a0[1] += bfhi(v0.x);
      a0[2] += bflo(v0.y); a0[3] += bfhi(v0.y);
      a0[4] += bflo(v0.z); a0[5] += bfhi(v0.z);
      a0[6] += bflo(v0.w); a0[7] += bfhi(v0.w);
      a1[0] += bflo(v1.x); a1[1] += bfhi(v1.x);
      a1[2] += bflo(v1.y); a1[3] += bfhi(v1.y);
      a1[4] += bflo(v1.z); a1[5] += bfhi(v1.z);
      a1[6] += bflo(v1.w); a1[7] += bfhi(v1.w);
    }
    if (ei < num) {                              // tail edge for this group
      const int s = srt[beg + ei];
      const uint4 v = *(const uint4*)(yb + (size_t)s * DIM + lsub * 8);
      a0[0] += bflo(v.x); a0[1] += bfhi(v.x);
      a0[2] += bflo(v.y); a0[3] += bfhi(v.y);
      a0[4] += bflo(v.z); a0[5] += bfhi(v.z);
      a0[6] += bflo(v.w); a0[7] += bfhi(v.w);
    }
    float r[8];
#pragma unroll
    for (int d = 0; d < 8; ++d) {
      float s = a0[d] + a1[d];
      s += __shfl_xor(s, 16);
      s += __shfl_xor(s, 32);
      r[d] = s;
    }
    if (grp == 0) {
      const float ic = 1.0f / fmaxf((float)num, 1.0f);
      const unsigned int o0 =
          ((unsigned int)f2bf(r[1] * ic) << 16) | f2bf(r[0] * ic);
      const unsigned int o1 =
          ((unsigned int)f2bf(r[3] * ic) << 16) | f2bf(r[2] * ic);
      const unsigned int o2 =
          ((unsigned int)f2bf(r[5] * ic) << 16) | f2bf(r[4] * ic);
      const unsigned int o3 =
          ((unsigned int)f2bf(r[7] * ic) << 16) | f2bf(r[6] * ic);
      *(uint4*)&msg_lds[c * 136 + lsub * 8] = make_uint4(o0, o1, o2, o3);
    }
  }

  // ---- P3a: stage A (fp32 -> bf16, XOR-swizzled); srt is dead now ----
  {
    const int row  = t >> 2;
    const int h    = t & 3;
    const int grow = row0 + row;
    const bool ok  = grow < N_CELL;
    const float* xrow = xc + (size_t)grow * DIM;
#pragma unroll
    for (int i = 0; i < 2; ++i) {
      const int kk = h * 32 + i * 16;
      float4 f0, f1, f2, f3;
      if (ok) {
        f0 = *(const float4*)(xrow + kk);
        f1 = *(const float4*)(xrow + kk + 4);
        f2 = *(const float4*)(xrow + kk + 8);
        f3 = *(const float4*)(xrow + kk + 12);
      } else {
        f0 = f1 = f2 = f3 = make_float4(0.f, 0.f, 0.f, 0.f);
      }
      const float fv[16] = {f0.x, f0.y, f0.z, f0.w, f1.x, f1.y, f1.z, f1.w,
                            f2.x, f2.y, f2.z, f2.w, f3.x, f3.y, f3.z, f3.w};
      union { unsigned short u[16]; uint4 q[2]; } pk;
#pragma unroll
      for (int q = 0; q < 16; ++q) pk.u[q] = f2bf(fv[q]);
      const int s0 = ((kk >> 3) + 0) ^ (row & 15);
      const int s1 = ((kk >> 3) + 1) ^ (row & 15);
      *(uint4*)&a_lds[row * 128 + s0 * 8] = pk.q[0];
      *(uint4*)&a_lds[row * 128 + s1 * 8] = pk.q[1];
    }
  }
  __syncthreads();   // A visible to all; msg_lds writes also visible past here

  // ---- P3b: MFMA; wave w owns cols [w*32, w*32+32) ----
  const int l15 = l & 15, lq = l >> 4;
  f32x4 acc[4][2];
#pragma unroll
  for (int g = 0; g < 4; ++g)
#pragma unroll
    for (int c = 0; c < 2; ++c) acc[g][c] = (f32x4){0.f, 0.f, 0.f, 0.f};

#pragma unroll
  for (int ks = 0; ks < 4; ++ks) {
    bf16x8 bfr[2];
#pragma unroll
    for (int c = 0; c < 2; ++c) {
      const int cf = w * 2 + c;
      bfr[c] = *(const bf16x8*)(wb + (size_t)(((ks * 8 + cf) * 64 + l) * 8));
    }
    bf16x8 afr[4];
#pragma unroll
    for (int g = 0; g < 4; ++g) {
      const int row = g * 16 + l15;
      const int s   = (ks * 4 + lq) ^ l15;
      afr[g] = *(const bf16x8*)&a_lds[row * 128 + s * 8];
    }
#pragma unroll
    for (int g = 0; g < 4; ++g)
#pragma unroll
      for (int c = 0; c < 2; ++c)
        acc[g][c] = __builtin_amdgcn_mfma_f32_16x16x32_bf16(
            afr[g], bfr[c], acc[g][c], 0, 0, 0);
  }

  // ---- P4: val = acc + msg + bias, in-place into msg_lds; BN sums ----
  // Each (row,col) element is read AND written only by its fragment owner.
  float csum[2] = {0.f, 0.f}, csq[2] = {0.f, 0.f};
#pragma unroll
  for (int g = 0; g < 4; ++g) {
#pragma unroll
    for (int c = 0; c < 2; ++c) {
      const int col = (w * 2 + c) * 16 + l15;
      const float bbl = bl[col];
#pragma unroll
      for (int r = 0; r < 4; ++r) {
        const int row  = g * 16 + lq * 4 + r;
        const int grow = row0 + row;
        if (grow < N_CELL) {
          const int idx = row * 136 + col;
          const float val = acc[g][c][r] + bf2f(msg_lds[idx]) + bbl;
          msg_lds[idx] = f2bf(val);
          csum[c] += val;
          csq[c]  += val * val;
        }
      }
    }
  }
#pragma unroll
  for (int c = 0; c < 2; ++c) {
    csum[c] += __shfl_xor(csum[c], 16);
    csum[c] += __shfl_xor(csum[c], 32);
    csq[c]  += __shfl_xor(csq[c], 16);
    csq[c]  += __shfl_xor(csq[c], 32);
  }
  if (lq == 0) {
#pragma unroll
    for (int c = 0; c < 2; ++c) {
      ps[w][c * 16 + l15]  = csum[c];   // col = w*32 + c*16 + l15
      ps2[w][c * 16 + l15] = csq[c];
    }
  }
  __syncthreads();

  // ---- P5: vectorized store msg_lds -> preb; BN atomics ----
  {
    const int grow = row0 + l;
    if (grow < N_CELL) {
      unsigned short* prow = preb + (size_t)grow * DIM + w * 32;
      const unsigned short* mrow = msg_lds + l * 136 + w * 32;
#pragma unroll
      for (int i = 0; i < 4; ++i)
        *(uint4*)(prow + i * 8) = *(const uint4*)(mrow + i * 8);
    }
    const int which = t >> 7;          // 0: sum, 1: sumsq
    const int col   = t & 127;
    const int wi    = col >> 5;
    const int idx   = col & 31;
    const float v = which ? ps2[wi][idx] : ps[wi][idx];
    unsafeAtomicAdd(&stats[t], v);     // t in [0,256)
  }
}

// ---------------------------------------------------------------------------
// bn_finalize: mu / inv_std from accumulated sums (1 block, ~2 us)
// ---------------------------------------------------------------------------
__global__ __launch_bounds__(128) void bn_finalize(float* __restrict__ stats) {
  const int j = threadIdx.x;
  const float mu  = stats[j] / (float)N_CELL;
  const float var = stats[128 + j] / (float)N_CELL - mu * mu;
  stats[256 + j] = mu;
  stats[384 + j] = rsqrtf(var + EPS_BN);
}

// ---------------------------------------------------------------------------
// bn_apply: read bf16 pre (L2/L3-hot), write fp32 out
// ---------------------------------------------------------------------------
__global__ __launch_bounds__(256) void bn_apply(
    const unsigned short* __restrict__ preb, float* __restrict__ out,
    const float* __restrict__ stats) {
  const size_t total = (size_t)N_CELL * DIM / 8;
  const size_t step  = (size_t)gridDim.x * blockDim.x;
  for (size_t i = (size_t)blockIdx.x * blockDim.x + threadIdx.x; i < total;
       i += step) {
    const uint4 v = ((const uint4*)preb)[i];
    const int col = (int)((i * 8) & (DIM - 1));
    const float* mu = stats + 256 + col;
    const float* is = stats + 384 + col;
    float4 o0, o1;
    o0.x = (bflo(v.x) - mu[0]) * is[0];
    o0.y = (bfhi(v.x) - mu[1]) * is[1];
    o0.z = (bflo(v.y) - mu[2]) * is[2];
    o0.w = (bfhi(v.y) - mu[3]) * is[3];
    o1.x = (bflo(v.z) - mu[4]) * is[4];
    o1.y = (bfhi(v.z) - mu[5]) * is[5];
    o1.z = (bflo(v.w) - mu[6]) * is[6];
    o1.w = (bfhi(v.w) - mu[7]) * is[7];
    *(float4*)(out + i * 8)     = o0;
    *(float4*)(out + i * 8 + 4) = o1;
  }
}

// ---------------------------------------------------------------------------
extern "C" void kernel_launch(void* const* d_in, const int* in_sizes, int n_in,
                              void* d_out, int out_size, void* d_ws,
                              size_t ws_size, hipStream_t stream) {
  const float* x_cell = (const float*)d_in[0];
  const float* x_gene = (const float*)d_in[1];
  const float* Wl_gc  = (const float*)d_in[2];
  const float* bl_gc  = (const float*)d_in[3];
  const float* Wr_gc  = (const float*)d_in[4];
  // d_in[5..7] (cg weights) are dead: the gene branch never feeds the output.
  const int* gc_src = (const int*)d_in[8];
  const int* gc_dst = (const int*)d_in[9];
  const int  E      = in_sizes[8];

  const float* Wl1 = Wl_gc + DIM * DIM;   // layer 1 (last)
  const float* bl1 = bl_gc + DIM;
  const float* Wr1 = Wr_gc + DIM * DIM;

  float* ws    = (float*)d_ws;
  float* stats = ws + WS_STATS;
  int*   gcur  = (int*)(ws + WS_GCUR);
  unsigned short* preb   = (unsigned short*)(ws + WS_PREB);
  unsigned short* ygene  = (unsigned short*)(ws + WS_YGENE);
  unsigned int*   gedges = (unsigned int*)(ws + WS_GEDGE);
  unsigned short* Wb     = (unsigned short*)(ws + WS_WB);
  float* out   = (float*)d_out;

  // zero stats + bucket counters (8 KB)
  hipMemsetAsync(d_ws, 0, (size_t)WS_ZERO * sizeof(float), stream);

  prep_fused<<<NPART + NCONV + NYG, 256, 0, stream>>>(
      gc_src, gc_dst, gcur, gedges, Wr1, Wb, x_gene, Wl1, ygene, E);

  gemm_fused<<<NBUCKET, 256, 0, stream>>>(gedges, gcur, ygene, x_cell, Wb,
                                          bl1, preb, stats);

  bn_finalize<<<1, 128, 0, stream>>>(stats);
  bn_apply<<<2048, 256, 0, stream>>>(preb, out, stats);
}